// Round 1
// baseline (160.901 us; speedup 1.0000x reference)
//
#include <hip/hip_runtime.h>
#include <cmath>

#define FIN 256
#define FQK 256
#define SCALING 0.0625f  // FQK^-0.5 = 1/16
#define MAX_SEG 256

typedef __bf16 bf16_t;
typedef bf16_t bf16x8 __attribute__((ext_vector_type(8)));
typedef float  f32x4  __attribute__((ext_vector_type(4)));

__device__ __forceinline__ unsigned short f2bf(float f) {
    unsigned int u = __float_as_uint(f);
    u += 0x7FFFu + ((u >> 16) & 1u);   // RNE
    return (unsigned short)(u >> 16);
}
__device__ __forceinline__ float bf_lo(unsigned int w) { return __uint_as_float(w << 16); }
__device__ __forceinline__ float bf_hi(unsigned int w) { return __uint_as_float(w & 0xFFFF0000u); }

// native cast is RNE on gfx950 -> v_cvt_pk_bf16_f32 pairs (compiler-formed)
__device__ __forceinline__ bf16x8 cvt8(float4 a, float4 b) {
    bf16x8 r;
    r[0] = (bf16_t)a.x; r[1] = (bf16_t)a.y; r[2] = (bf16_t)a.z; r[3] = (bf16_t)a.w;
    r[4] = (bf16_t)b.x; r[5] = (bf16_t)b.y; r[6] = (bf16_t)b.z; r[7] = (bf16_t)b.w;
    return r;
}

// ---------------------------------------------------------------------------
// Kernel 1 (fused): blocks [0,FIN) compute Mb[f][g] = bf16(SCALING * sum_c
// W[c][f]*W[256+c][g]); blocks [FIN, FIN+segBlocks) compute
// seg[n] = lower_bound(src, n).  Independent work, one launch.
// ---------------------------------------------------------------------------
__global__ __launch_bounds__(256) void m_seg_kernel(const float* __restrict__ W,
                                                    unsigned short* __restrict__ Mb,
                                                    const int* __restrict__ src,
                                                    int* __restrict__ seg, int N, int E) {
    const int b = blockIdx.x;
    if (b < FIN) {
        const int f = b;
        const int g = threadIdx.x;
        const float* __restrict__ Wq = W;              // scalar (block-uniform) loads
        const float* __restrict__ Wk = W + FQK * FIN;  // coalesced loads
        float acc = 0.f;
#pragma unroll 8
        for (int c = 0; c < FQK; ++c)
            acc += Wq[c * FIN + f] * Wk[c * FIN + g];
        Mb[f * FIN + g] = f2bf(acc * SCALING);
    } else {
        const int n = (b - FIN) * 256 + threadIdx.x;
        if (n > N) return;
        int lo = 0, hi = E;
        while (lo < hi) {
            const int mid = (lo + hi) >> 1;
            if (src[mid] < n) lo = mid + 1; else hi = mid;
        }
        seg[n] = lo;
    }
}

// ---------------------------------------------------------------------------
// Kernel 2: y[n][f] = sum_g x[n][g] * M[g][f], bf16 MFMA (16x16x32).
// No LDS, no barriers: A-fragment loaded directly from global x
// (lane m16 -> row, quad q -> k-offset; 2x float4 + cvt_pk to bf16).
// 16 rows/block, 4 waves split f into 64-wide slices -> 1250 blocks
// (4.9 blocks/CU vs 1.2 before); K fully unrolled so loads pipeline.
// ---------------------------------------------------------------------------
__global__ __launch_bounds__(256) void gemm_y_kernel(const float* __restrict__ x,
                                                     const unsigned short* __restrict__ Mb,
                                                     unsigned short* __restrict__ y, int N) {
    const int t    = threadIdx.x;
    const int wv   = t >> 6;
    const int lane = t & 63;
    const int q    = lane >> 4;    // quad 0..3 -> k-offset q*8
    const int m16  = lane & 15;    // row within 16-tile / output col
    const int n0   = blockIdx.x * 16;
    const int f0   = wv * 64;

    const int row  = n0 + m16;
    const int rowc = row < N ? row : N - 1;            // clamp (stores are guarded)
    const float* __restrict__ xr = x + (size_t)rowc * FIN;

    f32x4 acc[4] = {};

#pragma unroll
    for (int kc = 0; kc < FIN; kc += 32) {
        const float4 a0 = *(const float4*)(xr + kc + q * 8);
        const float4 a1 = *(const float4*)(xr + kc + q * 8 + 4);
        const bf16x8 af = cvt8(a0, a1);
#pragma unroll
        for (int ft = 0; ft < 4; ++ft) {
            const int f = f0 + ft * 16 + m16;
            union { uint4 u; bf16x8 v; } bu;
            bu.u = *(const uint4*)(Mb + (size_t)f * FIN + kc + q * 8);
            acc[ft] = __builtin_amdgcn_mfma_f32_16x16x32_bf16(af, bu.v, acc[ft], 0, 0, 0);
        }
    }

    // D layout: col = m16, row = q*4 + r within the 16x16 tile
#pragma unroll
    for (int r = 0; r < 4; ++r) {
        const int n = n0 + q * 4 + r;
        if (n < N) {
#pragma unroll
            for (int ft = 0; ft < 4; ++ft)
                y[(size_t)n * FIN + f0 + ft * 16 + m16] = f2bf(acc[ft][r]);
        }
    }
}

// ---------------------------------------------------------------------------
// Kernel 3: one wave per node. 8-lane groups (g=lane>>3, j=lane&7):
// 8 edges in flight per iteration, each lane holds 64B contiguous of the
// gathered y[dest] row (4 outstanding uint4 loads/lane vs 2 before).
// dest indices read directly per iteration (group-uniform broadcast load,
// L1-hot) -> no shfl on the address critical path.  Tail groups are
// predicated off uniformly (no wasted gathers).
// ---------------------------------------------------------------------------
__device__ __forceinline__ float dot8(uint4 qv, float4 xa, float4 xb) {
    return bf_lo(qv.x) * xa.x + bf_hi(qv.x) * xa.y
         + bf_lo(qv.y) * xa.z + bf_hi(qv.y) * xa.w
         + bf_lo(qv.z) * xb.x + bf_hi(qv.z) * xb.y
         + bf_lo(qv.w) * xb.z + bf_hi(qv.w) * xb.w;
}

__global__ __launch_bounds__(256) void node_edge_kernel(const float* __restrict__ x,
                                                        const unsigned short* __restrict__ y,
                                                        const int* __restrict__ dest,
                                                        const int* __restrict__ seg,
                                                        float* __restrict__ out, int N) {
    __shared__ float exlds[4][MAX_SEG];

    const int w    = threadIdx.x >> 6;
    const int lane = threadIdx.x & 63;
    const int n    = blockIdx.x * 4 + w;
    const int g    = lane >> 3;    // edge slot 0..7
    const int j    = lane & 7;     // 64B slice of the row

    int   s0 = 0, cnt = 0;
    float inv = 0.f;

    if (n < N) {
        s0  = seg[n];
        cnt = seg[n + 1] - s0;
    }

    if (cnt > 0) {
        // x[n] slice for this lane: k = j*32 .. j*32+32 (fp32, stays exact)
        float4 xf[8];
        const float* __restrict__ xr = x + (size_t)n * FIN + j * 32;
#pragma unroll
        for (int u = 0; u < 8; ++u) xf[u] = *(const float4*)(xr + u * 4);

        float sum = 0.f;
        const int nit = (cnt + 7) >> 3;
        for (int it = 0; it < nit; ++it) {
            const int i = it * 8 + g;          // edge index within segment
            if (i < cnt) {                     // uniform within each 8-lane group
                const int d = dest[s0 + i];
                const uint4* __restrict__ yr =
                    (const uint4*)(y + (size_t)d * FIN) + j * 4;
                const uint4 q0 = yr[0];
                const uint4 q1 = yr[1];
                const uint4 q2 = yr[2];
                const uint4 q3 = yr[3];
                float acc = dot8(q0, xf[0], xf[1]) + dot8(q1, xf[2], xf[3])
                          + dot8(q2, xf[4], xf[5]) + dot8(q3, xf[6], xf[7]);
                acc += __shfl_xor(acc, 1, 64);
                acc += __shfl_xor(acc, 2, 64);
                acc += __shfl_xor(acc, 4, 64);
                const float ex = __expf(acc);
                sum += ex;
                if (j == 0 && i < MAX_SEG) exlds[w][i] = ex;
            }
        }
        // groups hold identical sums internally; combine the 8 groups
        sum += __shfl_xor(sum, 8, 64);
        sum += __shfl_xor(sum, 16, 64);
        sum += __shfl_xor(sum, 32, 64);
        inv = 1.0f / sum;
    }

    __syncthreads();

    if (cnt > 0) {
        const int lim = cnt < MAX_SEG ? cnt : MAX_SEG;
        for (int i = lane; i < lim; i += 64)
            out[s0 + i] = exlds[w][i] * inv;
    }
}

// ---------------------------------------------------------------------------
extern "C" void kernel_launch(void* const* d_in, const int* in_sizes, int n_in,
                              void* d_out, int out_size, void* d_ws, size_t ws_size,
                              hipStream_t stream) {
    const float* x  = (const float*)d_in[0];
    const int*   ei = (const int*)d_in[1];
    const float* W  = (const float*)d_in[2];
    float* out = (float*)d_out;

    const int N = in_sizes[0] / FIN;
    const int E = in_sizes[1] / 2;

    // workspace layout
    unsigned short* Mb  = (unsigned short*)d_ws;                // 256*256 bf16
    unsigned short* y   = Mb + (size_t)FIN * FIN;               // N*256 bf16
    int*            seg = (int*)(y + (size_t)N * FIN);          // N+1

    const int segBlocks = (N + 256) / 256;                      // covers n = 0..N
    m_seg_kernel<<<FIN + segBlocks, 256, 0, stream>>>(W, Mb, ei, seg, N, E);

    gemm_y_kernel<<<(N + 15) / 16, 256, 0, stream>>>(x, Mb, y, N);

    node_edge_kernel<<<(N + 3) / 4, 256, 0, stream>>>(x, y, ei + E, seg, out, N);
}

// Round 2
// 137.063 us; speedup vs baseline: 1.1739x; 1.1739x over previous
//
#include <hip/hip_runtime.h>
#include <cmath>

#define FIN 256
#define FQK 256
#define SCALING 0.0625f  // FQK^-0.5 = 1/16
#define MAX_SEG 256
#define ASTRIDE 264      // bf16 elems per LDS row: 528 B = 33*16 (b128-aligned, 2-way banks)

typedef __bf16 bf16_t;
typedef bf16_t bf16x8 __attribute__((ext_vector_type(8)));
typedef float  f32x4  __attribute__((ext_vector_type(4)));

__device__ __forceinline__ unsigned short f2bf(float f) {
    unsigned int u = __float_as_uint(f);
    u += 0x7FFFu + ((u >> 16) & 1u);   // RNE
    return (unsigned short)(u >> 16);
}
__device__ __forceinline__ float bf_lo(unsigned int w) { return __uint_as_float(w << 16); }
__device__ __forceinline__ float bf_hi(unsigned int w) { return __uint_as_float(w & 0xFFFF0000u); }

// native cast is RNE on gfx950 -> v_cvt_pk_bf16_f32 pairs (compiler-formed)
__device__ __forceinline__ bf16x8 cvt8(float4 a, float4 b) {
    bf16x8 r;
    r[0] = (bf16_t)a.x; r[1] = (bf16_t)a.y; r[2] = (bf16_t)a.z; r[3] = (bf16_t)a.w;
    r[4] = (bf16_t)b.x; r[5] = (bf16_t)b.y; r[6] = (bf16_t)b.z; r[7] = (bf16_t)b.w;
    return r;
}

// ---------------------------------------------------------------------------
// Kernel 1 (fused): blocks [0,FIN): MbF (B-fragment-swizzled M matrix)
//   M[f][k] = SCALING * sum_c W[c][f] * W[256+c][k], stored so that the
//   gemm's B-fragment load is coalesced:
//   flat_idx = (((k>>5)*16 + (f>>4))*64 + ((k>>3)&3)*16 + (f&15))*8 + (k&7)
// blocks [FIN, FIN+segBlocks): seg[n] = lower_bound(src, n).
// ---------------------------------------------------------------------------
__global__ __launch_bounds__(256) void m_seg_kernel(const float* __restrict__ W,
                                                    unsigned short* __restrict__ MbF,
                                                    const int* __restrict__ src,
                                                    int* __restrict__ seg, int N, int E) {
    const int b = blockIdx.x;
    if (b < FIN) {
        const int f = b;
        const int k = threadIdx.x;
        const float* __restrict__ Wq = W;              // block-uniform loads
        const float* __restrict__ Wk = W + FQK * FIN;  // coalesced loads
        float acc = 0.f;
#pragma unroll 8
        for (int c = 0; c < FQK; ++c)
            acc += Wq[c * FIN + f] * Wk[c * FIN + k];
        const int ft  = f >> 4, m16 = f & 15;
        const int kcI = k >> 5, q = (k >> 3) & 3, e = k & 7;
        MbF[(size_t)(((kcI * 16 + ft) * 64 + q * 16 + m16) * 8 + e)] = f2bf(acc * SCALING);
    } else {
        const int n = (b - FIN) * 256 + threadIdx.x;
        if (n > N) return;
        int lo = 0, hi = E;
        while (lo < hi) {
            const int mid = (lo + hi) >> 1;
            if (src[mid] < n) lo = mid + 1; else hi = mid;
        }
        seg[n] = lo;
    }
}

// ---------------------------------------------------------------------------
// Kernel 2: y[n][f] = sum_k x[n][k] * M[f][k], bf16 MFMA (16x16x32).
// 32 rows/block (625 blocks = 2.4/CU), 4 waves split f into 64-wide slices.
// Whole 32x256 A-tile staged fp32->bf16 in LDS ONCE (single barrier/block);
// B-fragments read coalesced (1KB/wave-instr) from the swizzled MbF (L2-hot).
// ---------------------------------------------------------------------------
__global__ __launch_bounds__(256) void gemm_y_kernel(const float* __restrict__ x,
                                                     const unsigned short* __restrict__ MbF,
                                                     unsigned short* __restrict__ y, int N) {
    __shared__ unsigned short sA[32 * ASTRIDE];

    const int t    = threadIdx.x;
    const int wv   = t >> 6;
    const int lane = t & 63;
    const int q    = lane >> 4;    // quad 0..3 -> k-offset q*8
    const int m16  = lane & 15;
    const int n0   = blockIdx.x * 32;
    const int f0   = wv * 64;

    // ---- stage A: thread t -> row t>>3, cols (t&7)*32 .. +32 (fp32 -> bf16)
    {
        const int srow = t >> 3;
        const int scol = (t & 7) * 32;
        const int n    = n0 + srow;
        const int nc   = n < N ? n : N - 1;            // clamp; bad rows never stored
        const float* __restrict__ xp = x + (size_t)nc * FIN + scol;
        unsigned short* __restrict__ sp = &sA[srow * ASTRIDE + scol];
#pragma unroll
        for (int u = 0; u < 4; ++u) {
            const float4 a = *(const float4*)(xp + u * 8);
            const float4 b = *(const float4*)(xp + u * 8 + 4);
            *(bf16x8*)(sp + u * 8) = cvt8(a, b);
        }
    }
    __syncthreads();   // the only barrier; LDS read-only afterwards

    f32x4 acc[2][4] = {};   // [m-tile][f-tile]

#pragma unroll
    for (int kc = 0; kc < FIN; kc += 32) {
        bf16x8 afrag[2];
#pragma unroll
        for (int mt = 0; mt < 2; ++mt)
            afrag[mt] = *(const bf16x8*)&sA[(mt * 16 + m16) * ASTRIDE + kc + q * 8];

        // coalesced B-fragments: base for this (kc, wave) + ft*512 elems
        const unsigned short* __restrict__ bp =
            MbF + (size_t)(((kc >> 5) * 16 + (f0 >> 4)) * 64 + lane) * 8;
#pragma unroll
        for (int ft = 0; ft < 4; ++ft) {
            union { uint4 u; bf16x8 v; } bu;
            bu.u = *(const uint4*)(bp + ft * 512);
#pragma unroll
            for (int mt = 0; mt < 2; ++mt)
                acc[mt][ft] = __builtin_amdgcn_mfma_f32_16x16x32_bf16(afrag[mt], bu.v,
                                                                     acc[mt][ft], 0, 0, 0);
        }
    }

    // ---- store: D[row][col]: col = m16, row = q*4 + r within each 16x16 tile
#pragma unroll
    for (int mt = 0; mt < 2; ++mt) {
#pragma unroll
        for (int r = 0; r < 4; ++r) {
            const int n = n0 + mt * 16 + q * 4 + r;
            if (n < N) {
#pragma unroll
                for (int ft = 0; ft < 4; ++ft)
                    y[(size_t)n * FIN + f0 + ft * 16 + m16] = f2bf(acc[mt][ft][r]);
            }
        }
    }
}

// ---------------------------------------------------------------------------
// Kernel 3: one wave per node, 8-lane groups (g=edge slot, j=64B row slice),
// 2-deep software pipeline: next iteration's dest + 4 gather uint4s issued
// before consuming the current ones (hides gather latency under compute).
// ---------------------------------------------------------------------------
__device__ __forceinline__ float dot8(uint4 qv, float4 xa, float4 xb) {
    return bf_lo(qv.x) * xa.x + bf_hi(qv.x) * xa.y
         + bf_lo(qv.y) * xa.z + bf_hi(qv.y) * xa.w
         + bf_lo(qv.z) * xb.x + bf_hi(qv.z) * xb.y
         + bf_lo(qv.w) * xb.z + bf_hi(qv.w) * xb.w;
}

__global__ __launch_bounds__(256) void node_edge_kernel(const float* __restrict__ x,
                                                        const unsigned short* __restrict__ y,
                                                        const int* __restrict__ dest,
                                                        const int* __restrict__ seg,
                                                        float* __restrict__ out, int N) {
    __shared__ float exlds[4][MAX_SEG];

    const int w    = threadIdx.x >> 6;
    const int lane = threadIdx.x & 63;
    const int n    = blockIdx.x * 4 + w;
    const int g    = lane >> 3;    // edge slot 0..7
    const int j    = lane & 7;     // 64B slice of the row

    int   s0 = 0, cnt = 0;
    float inv = 0.f;

    if (n < N) {
        s0  = seg[n];
        cnt = seg[n + 1] - s0;
    }

    if (cnt > 0) {
        // x[n] slice for this lane: k = j*32 .. +32 (fp32, exact)
        float4 xf[8];
        const float* __restrict__ xr = x + (size_t)n * FIN + j * 32;
#pragma unroll
        for (int u = 0; u < 8; ++u) xf[u] = *(const float4*)(xr + u * 4);

        float sum = 0.f;
        const int nit = (cnt + 7) >> 3;

        // ---- pipeline prologue: gathers for iteration 0
        uint4 c0, c1, c2, c3;
        bool vc = g < cnt;
        if (vc) {
            const int d = dest[s0 + g];
            const uint4* __restrict__ yr = (const uint4*)(y + (size_t)d * FIN) + j * 4;
            c0 = yr[0]; c1 = yr[1]; c2 = yr[2]; c3 = yr[3];
        }

        for (int it = 0; it < nit; ++it) {
            const int i   = it * 8 + g;
            const int inx = i + 8;
            const bool vn = inx < cnt;
            uint4 p0, p1, p2, p3;
            if (vn) {                               // issue next-iteration gathers
                const int d = dest[s0 + inx];
                const uint4* __restrict__ yr = (const uint4*)(y + (size_t)d * FIN) + j * 4;
                p0 = yr[0]; p1 = yr[1]; p2 = yr[2]; p3 = yr[3];
            }
            if (vc) {                               // consume current
                float acc = dot8(c0, xf[0], xf[1]) + dot8(c1, xf[2], xf[3])
                          + dot8(c2, xf[4], xf[5]) + dot8(c3, xf[6], xf[7]);
                acc += __shfl_xor(acc, 1, 64);
                acc += __shfl_xor(acc, 2, 64);
                acc += __shfl_xor(acc, 4, 64);
                const float ex = __expf(acc);
                sum += ex;
                if (j == 0 && i < MAX_SEG) exlds[w][i] = ex;
            }
            c0 = p0; c1 = p1; c2 = p2; c3 = p3; vc = vn;
        }
        // groups hold identical sums internally; combine the 8 groups
        sum += __shfl_xor(sum, 8, 64);
        sum += __shfl_xor(sum, 16, 64);
        sum += __shfl_xor(sum, 32, 64);
        inv = 1.0f / sum;
    }

    __syncthreads();

    if (cnt > 0) {
        const int lim = cnt < MAX_SEG ? cnt : MAX_SEG;
        for (int i = lane; i < lim; i += 64)
            out[s0 + i] = exlds[w][i] * inv;
    }
}

// ---------------------------------------------------------------------------
extern "C" void kernel_launch(void* const* d_in, const int* in_sizes, int n_in,
                              void* d_out, int out_size, void* d_ws, size_t ws_size,
                              hipStream_t stream) {
    const float* x  = (const float*)d_in[0];
    const int*   ei = (const int*)d_in[1];
    const float* W  = (const float*)d_in[2];
    float* out = (float*)d_out;

    const int N = in_sizes[0] / FIN;
    const int E = in_sizes[1] / 2;

    // workspace layout
    unsigned short* MbF = (unsigned short*)d_ws;                // 256*256 bf16 (swizzled)
    unsigned short* y   = MbF + (size_t)FIN * FIN;              // N*256 bf16
    int*            seg = (int*)(y + (size_t)N * FIN);          // N+1

    const int segBlocks = (N + 256) / 256;                      // covers n = 0..N
    m_seg_kernel<<<FIN + segBlocks, 256, 0, stream>>>(W, MbF, ei, seg, N, E);

    gemm_y_kernel<<<(N + 31) / 32, 256, 0, stream>>>(x, MbF, y, N);

    node_edge_kernel<<<(N + 3) / 4, 256, 0, stream>>>(x, y, ei + E, seg, out, N);
}